// Round 17
// baseline (993.560 us; speedup 1.0000x reference)
//
#include <hip/hip_runtime.h>
#include <cstdint>
#include <cstddef>

typedef unsigned short u16;
typedef __bf16 bf16_t;
typedef bf16_t bf16x8 __attribute__((ext_vector_type(8)));
typedef float f32x4 __attribute__((ext_vector_type(4)));

#define NLAY 4
#define DMODEL 1280
#define NHEAD 16
#define HDIM 80
#define HDP 96           // padded head dim for QK^T K-loop (3 x 32)
#define MLPD 5120
#define LTOK 2048
#define SEGLEN 512

__device__ __forceinline__ u16 f2bf(float f) {
  union { float f; unsigned u; } x; x.f = f;
  unsigned r = x.u + 0x7fffu + ((x.u >> 16) & 1u);
  return (u16)(r >> 16);
}
__device__ __forceinline__ float bf2f(u16 s) {
  union { unsigned u; float f; } x; x.u = ((unsigned)s) << 16;
  return x.f;
}

#define GLOAD_LDS16(gsrc, ldst) \
  __builtin_amdgcn_global_load_lds((const __attribute__((address_space(1))) void*)(gsrc), \
                                   (__attribute__((address_space(3))) void*)(ldst), 16, 0, 0)

__device__ __forceinline__ void barrier_mem() {
  asm volatile("s_barrier" ::: "memory");
}

// ---------------- ALL weights fp32 -> bf16 convert (all 4 layers, ONE kernel) ----------
#define C0 (3 * DMODEL * DMODEL / 4)          // qkv_w float4s per layer
#define C1 (C0 + DMODEL * DMODEL / 4)         // + proj_w
#define C2 (C1 + MLPD * DMODEL / 4)           // + mlp_w1
#define C3 (C2 + DMODEL * MLPD / 4)           // + mlp_w2
__global__ __launch_bounds__(256) void cvt4all(const float* __restrict__ s_q,
                                               const float* __restrict__ s_p,
                                               const float* __restrict__ s_1,
                                               const float* __restrict__ s_2,
                                               u16* __restrict__ o_q, u16* __restrict__ o_p,
                                               u16* __restrict__ o_1, u16* __restrict__ o_2) {
  int gi = blockIdx.x * 256 + threadIdx.x;
  if (gi >= NLAY * C3) return;
  int l = gi / C3;
  int i = gi - l * C3;
  const float* src; u16* dst; int off;
  if (i < C0)      { src = s_q + (size_t)l * C0 * 4; dst = o_q + (size_t)l * C0 * 4;        off = i; }
  else if (i < C1) { src = s_p + (size_t)l * (C1 - C0) * 4; dst = o_p + (size_t)l * (C1 - C0) * 4; off = i - C0; }
  else if (i < C2) { src = s_1 + (size_t)l * (C2 - C1) * 4; dst = o_1 + (size_t)l * (C2 - C1) * 4; off = i - C1; }
  else             { src = s_2 + (size_t)l * (C3 - C2) * 4; dst = o_2 + (size_t)l * (C3 - C2) * 4; off = i - C2; }
  const float4 v = reinterpret_cast<const float4*>(src)[off];
  union { u16 s[4]; uint2 u; } o;
  o.s[0] = f2bf(v.x); o.s[1] = f2bf(v.y); o.s[2] = f2bf(v.z); o.s[3] = f2bf(v.w);
  reinterpret_cast<uint2*>(dst)[off] = o.u;
}

// ---------------- LayerNorm (fp32 in, bf16 out) ----------------
__global__ __launch_bounds__(256) void ln_bf16(const float* __restrict__ x,
                                               const float* __restrict__ g,
                                               const float* __restrict__ b,
                                               u16* __restrict__ out) {
  int row = blockIdx.x;
  int t = threadIdx.x;
  const float* xr = x + (size_t)row * DMODEL;
  float v[5]; float s = 0.f, s2 = 0.f;
#pragma unroll
  for (int i = 0; i < 5; i++) { v[i] = xr[t + i * 256]; s += v[i]; s2 += v[i] * v[i]; }
#pragma unroll
  for (int off = 32; off; off >>= 1) { s += __shfl_down(s, off); s2 += __shfl_down(s2, off); }
  __shared__ float ps[4], ps2[4];
  int w = t >> 6;
  if ((t & 63) == 0) { ps[w] = s; ps2[w] = s2; }
  __syncthreads();
  s = ps[0] + ps[1] + ps[2] + ps[3];
  s2 = ps2[0] + ps2[1] + ps2[2] + ps2[3];
  float mean = s * (1.f / DMODEL);
  float var = s2 * (1.f / DMODEL) - mean * mean;
  float inv = rsqrtf(var + 1e-6f);
#pragma unroll
  for (int i = 0; i < 5; i++) {
    int c = t + i * 256;
    out[(size_t)row * DMODEL + c] = f2bf((v[i] - mean) * inv * g[c] + b[c]);
  }
}

// ---- fused split-K reduce + residual + LayerNorm (vectorized, round-15) ----
__global__ __launch_bounds__(256) void reduce_ln(const u16* __restrict__ P,
                                                 const float* __restrict__ bias,
                                                 float* __restrict__ x,
                                                 const float* __restrict__ g,
                                                 const float* __restrict__ b,
                                                 u16* __restrict__ out) {
  int row = blockIdx.x;
  int t = threadIdx.x;
  const size_t PS = (size_t)LTOK * DMODEL;
  const size_t base = (size_t)row * DMODEL;
  const int c0 = t * 8;
  float v[8];
  float s = 0.f, s2 = 0.f;
  if (t < DMODEL / 8) {
    float4 x0 = *reinterpret_cast<const float4*>(x + base + c0);
    float4 x1 = *reinterpret_cast<const float4*>(x + base + c0 + 4);
    float4 b0 = *reinterpret_cast<const float4*>(bias + c0);
    float4 b1 = *reinterpret_cast<const float4*>(bias + c0 + 4);
    v[0] = x0.x + b0.x; v[1] = x0.y + b0.y; v[2] = x0.z + b0.z; v[3] = x0.w + b0.w;
    v[4] = x1.x + b1.x; v[5] = x1.y + b1.y; v[6] = x1.z + b1.z; v[7] = x1.w + b1.w;
#pragma unroll
    for (int z = 0; z < 4; z++) {
      uint4 pv = *reinterpret_cast<const uint4*>(P + z * PS + base + c0);
      const u16* ps = (const u16*)&pv;
#pragma unroll
      for (int e = 0; e < 8; e++) v[e] += bf2f(ps[e]);
    }
    float4 o0 = {v[0], v[1], v[2], v[3]};
    float4 o1 = {v[4], v[5], v[6], v[7]};
    *reinterpret_cast<float4*>(x + base + c0) = o0;
    *reinterpret_cast<float4*>(x + base + c0 + 4) = o1;
#pragma unroll
    for (int e = 0; e < 8; e++) { s += v[e]; s2 += v[e] * v[e]; }
  }
#pragma unroll
  for (int off = 32; off; off >>= 1) { s += __shfl_down(s, off); s2 += __shfl_down(s2, off); }
  __shared__ float psh[4], psh2[4];
  int w = t >> 6;
  if ((t & 63) == 0) { psh[w] = s; psh2[w] = s2; }
  __syncthreads();
  s = psh[0] + psh[1] + psh[2] + psh[3];
  s2 = psh2[0] + psh2[1] + psh2[2] + psh2[3];
  float mean = s * (1.f / DMODEL);
  float var = s2 * (1.f / DMODEL) - mean * mean;
  float inv = rsqrtf(var + 1e-6f);
  if (t < DMODEL / 8) {
    float4 g0 = *reinterpret_cast<const float4*>(g + c0);
    float4 g1 = *reinterpret_cast<const float4*>(g + c0 + 4);
    float4 e0 = *reinterpret_cast<const float4*>(b + c0);
    float4 e1 = *reinterpret_cast<const float4*>(b + c0 + 4);
    union { u16 h[8]; uint4 u; } o;
    o.h[0] = f2bf((v[0] - mean) * inv * g0.x + e0.x);
    o.h[1] = f2bf((v[1] - mean) * inv * g0.y + e0.y);
    o.h[2] = f2bf((v[2] - mean) * inv * g0.z + e0.z);
    o.h[3] = f2bf((v[3] - mean) * inv * g0.w + e0.w);
    o.h[4] = f2bf((v[4] - mean) * inv * g1.x + e1.x);
    o.h[5] = f2bf((v[5] - mean) * inv * g1.y + e1.y);
    o.h[6] = f2bf((v[6] - mean) * inv * g1.z + e1.z);
    o.h[7] = f2bf((v[7] - mean) * inv * g1.w + e1.w);
    *reinterpret_cast<uint4*>(out + base + c0) = o.u;
  }
}

// ---------------- deep-pipelined GEMM: 128Mx256N, BK=32, 8 waves, 3-buf counted vmcnt ----
// Hierarchical 4m x NBLKn tile-block ordering inside each XCD chunk.
// EPI 2: Cb = gelu(val + bias); EPI 3: Cb = val + bias
template <int EPI, int NBLK>
__global__ __launch_bounds__(512, 4) void gemmhp(const u16* __restrict__ A,
                                                 const u16* __restrict__ B,
                                                 const float* __restrict__ bias,
                                                 u16* __restrict__ Cb,
                                                 int M, int N, int K) {
  __shared__ u16 As[3][128 * 32];   // 24 KB
  __shared__ u16 Bs[3][256 * 32];   // 48 KB

  int gN = gridDim.x, gM = gridDim.y;
  int flat = blockIdx.x + gN * blockIdx.y;
  int nwg = gN * gM;
  int qc = nwg >> 3, rc = nwg & 7;
  int xcd = flat & 7, pos = flat >> 3;
  int start = (xcd < rc) ? xcd * (qc + 1) : rc * (qc + 1) + (xcd - rc) * qc;
  int swz = start + pos;
  int inn = swz % (4 * NBLK), blk = swz / (4 * NBLK);
  int mi = inn & 3, ni = inn >> 2;
  int bM = gM >> 2;
  int bmi = blk % bM, bni = blk / bM;
  int m0 = (bmi * 4 + mi) * 128;
  int n0 = (bni * NBLK + ni) * 256;

  int t = threadIdx.x, lane = t & 63, w = t >> 6;
  int wm = w >> 2, wn = w & 3;            // 2M x 4N waves, wave tile 64x64
  int r = lane & 15, kq = lane >> 4;
  f32x4 acc[4][4] = {};

  auto stageA = [&](int buf, int k0) {
    int row = t >> 2, s = t & 3;          // 512 chunks = 128 rows x 4 slots
    int ss = s ^ ((row >> 1) & 3);
    GLOAD_LDS16(A + (size_t)(m0 + row) * K + k0 + ss * 8, &As[buf][t * 8]);
  };
  auto stageB = [&](int buf, int k0) {
#pragma unroll
    for (int i = 0; i < 2; i++) {
      int chunk = i * 512 + t;            // 1024 chunks = 256 rows x 4 slots
      int row = chunk >> 2, s = chunk & 3;
      int ss = s ^ ((row >> 1) & 3);
      GLOAD_LDS16(B + (size_t)(n0 + row) * K + k0 + ss * 8, &Bs[buf][chunk * 8]);
    }
  };

  int NT = K >> 5;
  stageA(0, 0); stageB(0, 0);
  stageA(1, 32); stageB(1, 32);

  int bt = 0;
  for (int kt = 0; kt < NT; kt++) {
    if (kt == NT - 1) asm volatile("s_waitcnt vmcnt(0)" ::: "memory");
    else              asm volatile("s_waitcnt vmcnt(3)" ::: "memory");
    barrier_mem();                       // tile kt landed chip-wide
    const u16* as = As[bt];
    const u16* bs = Bs[bt];
    int b2 = bt + 2; if (b2 >= 3) b2 -= 3;
    bool st = (kt + 2) < NT;
    int k2 = (kt + 2) << 5;

    bf16x8 af[4], bfv[4];
#pragma unroll
    for (int i = 0; i < 4; i++) {
      int row = wm * 64 + i * 16 + r;
      int ss = kq ^ ((row >> 1) & 3);
      af[i] = *(const bf16x8*)&as[row * 32 + ss * 8];
    }
#pragma unroll
    for (int j = 0; j < 4; j++) {
      int row = wn * 64 + j * 16 + r;
      int ss = kq ^ ((row >> 1) & 3);
      bfv[j] = *(const bf16x8*)&bs[row * 32 + ss * 8];
    }
    if (st) { stageA(b2, k2); stageB(b2, k2); }
    __builtin_amdgcn_s_setprio(1);
#pragma unroll
    for (int i = 0; i < 4; i++)
#pragma unroll
      for (int j = 0; j < 4; j++)
        acc[i][j] = __builtin_amdgcn_mfma_f32_16x16x32_bf16(af[i], bfv[j], acc[i][j], 0, 0, 0);
    __builtin_amdgcn_s_setprio(0);

    bt++; if (bt == 3) bt = 0;
  }

#pragma unroll
  for (int i = 0; i < 4; i++) {
#pragma unroll
    for (int j = 0; j < 4; j++) {
      int col = n0 + wn * 64 + j * 16 + r;
      float bv = bias[col];
#pragma unroll
      for (int reg = 0; reg < 4; reg++) {
        int rowg = m0 + wm * 64 + i * 16 + kq * 4 + reg;
        float val = acc[i][j][reg] + bv;
        if (EPI == 2) {
          float z2 = -1.5957691216057308f * fmaf(0.044715f * val, val * val, val);
          float gg = val / (1.f + __expf(z2));
          Cb[(size_t)rowg * N + col] = f2bf(gg);
        } else {
          Cb[(size_t)rowg * N + col] = f2bf(val);
        }
      }
    }
  }
}

// ---------------- split-K deep-pipelined GEMM: 128x128, BK=32, 4 waves, bf16 partials --
// (round-12 proven: n-fastest XCD chunks, counted vmcnt(4), 3 buffers)
__global__ __launch_bounds__(256, 3) void gemmskb(const u16* __restrict__ A,
                                                  const u16* __restrict__ B,
                                                  u16* __restrict__ P,
                                                  int M, int N, int K, int KC) {
  __shared__ u16 As[3][128 * 32];   // 24 KB
  __shared__ u16 Bs[3][128 * 32];   // 24 KB

  int gN = gridDim.x, gM = gridDim.y;
  int flat = blockIdx.x + gN * blockIdx.y;
  int nwg = gN * gM;
  int qc = nwg >> 3, rc = nwg & 7;
  int xcd = flat & 7, pos = flat >> 3;
  int start = (xcd < rc) ? xcd * (qc + 1) : rc * (qc + 1) + (xcd - rc) * qc;
  int swz = start + pos;
  int n0 = (swz % gN) * 128;            // n-fastest within chunk
  int m0 = (swz / gN) * 128;
  int kbase = blockIdx.z * KC;
  u16* Pz = P + (size_t)blockIdx.z * M * N;

  int t = threadIdx.x, lane = t & 63, w = t >> 6;
  int wm = w >> 1, wn = w & 1;            // 2M x 2N waves, wave tile 64x64
  int r = lane & 15, kq = lane >> 4;
  f32x4 acc[4][4] = {};

  auto stage = [&](int buf, int k0) {
#pragma unroll
    for (int i = 0; i < 2; i++) {
      int chunk = i * 256 + t;            // 512 chunks = 128 rows x 4 slots
      int row = chunk >> 2, s = chunk & 3;
      int ss = s ^ ((row >> 1) & 3);
      GLOAD_LDS16(A + (size_t)(m0 + row) * K + k0 + ss * 8, &As[buf][chunk * 8]);
    }
#pragma unroll
    for (int i = 0; i < 2; i++) {
      int chunk = i * 256 + t;
      int row = chunk >> 2, s = chunk & 3;
      int ss = s ^ ((row >> 1) & 3);
      GLOAD_LDS16(B + (size_t)(n0 + row) * K + k0 + ss * 8, &Bs[buf][chunk * 8]);
    }
  };

  int NT = KC >> 5;
  stage(0, kbase);
  stage(1, kbase + 32);

  int bt = 0;
  for (int kt = 0; kt < NT; kt++) {
    if (kt == NT - 1) asm volatile("s_waitcnt vmcnt(0)" ::: "memory");
    else              asm volatile("s_waitcnt vmcnt(4)" ::: "memory");
    barrier_mem();                       // tile kt landed chip-wide
    const u16* as = As[bt];
    const u16* bs = Bs[bt];
    int b2 = bt + 2; if (b2 >= 3) b2 -= 3;
    bool st = (kt + 2) < NT;
    int k2 = kbase + ((kt + 2) << 5);

    bf16x8 af[4], bfv[4];
#pragma unroll
    for (int i = 0; i < 4; i++) {
      int row = wm * 64 + i * 16 + r;
      int ss = kq ^ ((row >> 1) & 3);
      af[i] = *(const bf16x8*)&as[row * 32 + ss * 8];
    }
#pragma unroll
    for (int j = 0; j < 4; j++) {
      int row = wn * 64 + j * 16 + r;
      int ss = kq ^ ((row >> 1) & 3);
      bfv[j] = *(const bf16x8*)&bs[row * 32 + ss * 8];
    }
    if (st) stage(b2, k2);
    __builtin_amdgcn_s_setprio(1);
#pragma unroll
    for (int i = 0; i < 4; i++)
#pragma unroll
      for (int j = 0; j < 4; j++)
        acc[i][j] = __builtin_amdgcn_mfma_f32_16x16x32_bf16(af[i], bfv[j], acc[i][j], 0, 0, 0);
    __builtin_amdgcn_s_setprio(0);

    bt++; if (bt == 3) bt = 0;
  }

#pragma unroll
  for (int i = 0; i < 4; i++) {
#pragma unroll
    for (int j = 0; j < 4; j++) {
      int col = n0 + wn * 64 + j * 16 + r;
#pragma unroll
      for (int reg = 0; reg < 4; reg++) {
        int rowg = m0 + wm * 64 + i * 16 + kq * 4 + reg;
        Pz[(size_t)rowg * N + col] = f2bf(acc[i][j][reg]);
      }
    }
  }
}

// ---------------- reduce 4 bf16 split-K partials + bias into residual x ----------------
#define N8TOT (LTOK * DMODEL / 8)
__global__ __launch_bounds__(256) void reduce4b(const u16* __restrict__ P,
                                                const float* __restrict__ bias,
                                                float4* __restrict__ x) {
  int i = blockIdx.x * 256 + threadIdx.x;
  if (i >= N8TOT) return;
  const size_t PS = (size_t)LTOK * DMODEL;
  float s[8] = {};
#pragma unroll
  for (int z = 0; z < 4; z++) {
    uint4 pv = *reinterpret_cast<const uint4*>(P + z * PS + (size_t)i * 8);
    const u16* ps = (const u16*)&pv;
#pragma unroll
    for (int e = 0; e < 8; e++) s[e] += bf2f(ps[e]);
  }
  int cb = (i % (DMODEL / 8)) * 8;
  float4 b0 = *reinterpret_cast<const float4*>(bias + cb);
  float4 b1 = *reinterpret_cast<const float4*>(bias + cb + 4);
  float4 xv0 = x[i * 2], xv1 = x[i * 2 + 1];
  xv0.x += s[0] + b0.x; xv0.y += s[1] + b0.y;
  xv0.z += s[2] + b0.z; xv0.w += s[3] + b0.w;
  xv1.x += s[4] + b1.x; xv1.y += s[5] + b1.y;
  xv1.z += s[6] + b1.z; xv1.w += s[7] + b1.w;
  x[i * 2] = xv0; x[i * 2 + 1] = xv1;
}

// ---- fused RoPE + V-transpose: one block per (head, 64-row tile) ----
// q,k: rope + pack into (NH, L, HDP) bf16 (q scaled); v: transpose to
// (NH, HD, L). Replaces rope_pack + vtrans (one dispatch fewer per layer).
__global__ __launch_bounds__(256) void rope_vt(const u16* __restrict__ qkv,
                                               const float* __restrict__ rpe,
                                               u16* __restrict__ qp,
                                               u16* __restrict__ kp,
                                               u16* __restrict__ vt) {
  int h = blockIdx.x >> 5;
  int lt = blockIdx.x & 31;
  int t = threadIdx.x;
  __shared__ float cs[64][40], sn[64][40];
  __shared__ u16 vld[64][81];
  const float scale = 0.11180339887498949f;  // 1/sqrt(80)

  // trig for 64 rows
#pragma unroll
  for (int e = 0; e < 10; e++) {
    int idx = t + e * 256;                 // 2560 = 64 x 40
    int ll = idx / 40, dm = idx - ll * 40;
    float a = rpe[(size_t)(lt * 64 + ll) * 40 + dm];
    cs[ll][dm] = cosf(a);
    sn[ll][dm] = sinf(a);
  }
  __syncthreads();

  // rope q,k for this head's 64 rows
#pragma unroll
  for (int e = 0; e < 40; e++) {
    int idx = t + e * 256;                 // 10240 = 64 rows x 2 x 80
    int ll = idx / 160, rem = idx - ll * 160;
    int which = rem / 80, d = rem - which * 80;
    int dm = (d < 40) ? d : d - 40;
    float c = cs[ll][dm], s = sn[ll][dm];
    const u16* row = qkv + (size_t)(lt * 64 + ll) * (3 * DMODEL) + which * DMODEL + h * HDIM;
    float v0 = bf2f(row[d]);
    float vr = (d < 40) ? -bf2f(row[d + 40]) : bf2f(row[d - 40]);
    float o = v0 * c + vr * s;
    if (which == 0) o *= scale;
    u16* dst = which ? kp : qp;
    dst[((size_t)h * LTOK + lt * 64 + ll) * HDP + d] = f2bf(o);
  }
  // zero pads [80,96)
#pragma unroll
  for (int e = 0; e < 8; e++) {
    int idx = t + e * 256;                 // 2048 = 64 x 2 x 16
    int ll = idx >> 5, rem = idx & 31;
    int which = rem >> 4, p = rem & 15;
    u16* dst = which ? kp : qp;
    dst[((size_t)h * LTOK + lt * 64 + ll) * HDP + HDIM + p] = 0;
  }

  // V transpose via LDS
#pragma unroll
  for (int e = 0; e < 20; e++) {
    int idx = t + e * 256;                 // 5120 = 64 x 80
    int ll = idx / 80, d = idx - ll * 80;
    vld[ll][d] = qkv[(size_t)(lt * 64 + ll) * (3 * DMODEL) + 2 * DMODEL + h * HDIM + d];
  }
  __syncthreads();
#pragma unroll
  for (int e = 0; e < 20; e++) {
    int idx = t + e * 256;
    int d = idx >> 6, ll = idx & 63;
    vt[((size_t)h * HDIM + d) * LTOK + lt * 64 + ll] = vld[ll][d];
  }
}

// ---------------- Attention: per (head, seg, 64-row q-tile) ----------------
__global__ __launch_bounds__(256) void attn(const u16* __restrict__ qp,
                                            const u16* __restrict__ kp,
                                            const u16* __restrict__ vt,
                                            u16* __restrict__ out) {
  int bid = blockIdx.x;               // h*32 + seg*8 + qt
  int h = bid >> 5;
  int seg = (bid >> 3) & 3;
  int qt = bid & 7;
  int t = threadIdx.x, w = t >> 6, lane = t & 63;
  int r = lane & 15, kq = lane >> 4;
  __shared__ u16 P[4][16][512];
  int seg0 = seg * SEGLEN;
  int q0 = seg0 + qt * 64 + w * 16;

  bf16x8 qf[3];
  const u16* qrow = qp + ((size_t)h * LTOK + q0 + r) * HDP;
#pragma unroll
  for (int kk = 0; kk < 3; kk++) qf[kk] = *(const bf16x8*)(qrow + kk * 32 + kq * 8);

  f32x4 sc[32];
#pragma unroll
  for (int j = 0; j < 32; j++) {
    f32x4 a = {0.f, 0.f, 0.f, 0.f};
    const u16* krow = kp + ((size_t)h * LTOK + seg0 + j * 16 + r) * HDP;
#pragma unroll
    for (int kk = 0; kk < 3; kk++) {
      bf16x8 bfr = *(const bf16x8*)(krow + kk * 32 + kq * 8);
      a = __builtin_amdgcn_mfma_f32_16x16x32_bf16(qf[kk], bfr, a, 0, 0, 0);
    }
    sc[j] = a;
  }

#pragma unroll
  for (int rr = 0; rr < 4; rr++) {
    float m = -1e30f;
#pragma unroll
    for (int j = 0; j < 32; j++) m = fmaxf(m, sc[j][rr]);
#pragma unroll
    for (int off = 1; off < 16; off <<= 1) m = fmaxf(m, __shfl_xor(m, off));
    float s = 0.f;
#pragma unroll
    for (int j = 0; j < 32; j++) { float e = __expf(sc[j][rr] - m); sc[j][rr] = e; s += e; }
#pragma unroll
    for (int off = 1; off < 16; off <<= 1) s += __shfl_xor(s, off);
    float inv = 1.f / s;
#pragma unroll
    for (int j = 0; j < 32; j++)
      P[w][kq * 4 + rr][j * 16 + r] = f2bf(sc[j][rr] * inv);
  }
  __syncthreads();

  f32x4 oc[5] = {};
#pragma unroll
  for (int tt = 0; tt < 16; tt++) {
    bf16x8 a = *(const bf16x8*)&P[w][r][tt * 32 + kq * 8];
#pragma unroll
    for (int n = 0; n < 5; n++) {
      const u16* vrow = vt + ((size_t)h * HDIM + n * 16 + r) * LTOK + seg0 + tt * 32 + kq * 8;
      bf16x8 bfr = *(const bf16x8*)vrow;
      oc[n] = __builtin_amdgcn_mfma_f32_16x16x32_bf16(a, bfr, oc[n], 0, 0, 0);
    }
  }
#pragma unroll
  for (int n = 0; n < 5; n++)
#pragma unroll
    for (int reg = 0; reg < 4; reg++) {
      int l = q0 + kq * 4 + reg;
      out[(size_t)l * DMODEL + h * HDIM + n * 16 + r] = f2bf(oc[n][reg]);
    }
}

// ---------------- host launch ----------------
extern "C" void kernel_launch(void* const* d_in, const int* in_sizes, int n_in,
                              void* d_out, int out_size, void* d_ws, size_t ws_size,
                              hipStream_t stream) {
  (void)in_sizes; (void)n_in; (void)out_size; (void)ws_size;
  const float* x_in   = (const float*)d_in[0];
  const float* rpe    = (const float*)d_in[1];
  const float* ln1_g  = (const float*)d_in[3];
  const float* ln1_b  = (const float*)d_in[4];
  const float* ln2_g  = (const float*)d_in[5];
  const float* ln2_b  = (const float*)d_in[6];
  const float* qkv_w  = (const float*)d_in[7];
  const float* qkv_b  = (const float*)d_in[8];
  const float* proj_w = (const float*)d_in[9];
  const float* proj_b = (const float*)d_in[10];
  const float* mlp_w1 = (const float*)d_in[11];
  const float* mlp_b1 = (const float*)d_in[12];
  const float* mlp_w2 = (const float*)d_in[13];
  const float* mlp_b2 = (const float*)d_in[14];
  float* x = (float*)d_out;

  char* ws = (char*)d_ws;
  size_t off = 0;
  auto alloc = [&](size_t bytes) -> char* {
    char* p = ws + off;
    off = (off + bytes + 255) & ~(size_t)255;
    return p;
  };
  // all-layer bf16 weight buffers
  u16* wq  = (u16*)alloc((size_t)NLAY * 3 * DMODEL * DMODEL * 2);
  u16* wp  = (u16*)alloc((size_t)NLAY * DMODEL * DMODEL * 2);
  u16* w1  = (u16*)alloc((size_t)NLAY * MLPD * DMODEL * 2);
  u16* w2  = (u16*)alloc((size_t)NLAY * DMODEL * MLPD * 2);
  u16* hb  = (u16*)alloc((size_t)LTOK * DMODEL * 2);
  u16* qkvb = (u16*)alloc((size_t)LTOK * 3 * DMODEL * 2);
  u16* qp  = (u16*)alloc((size_t)NHEAD * LTOK * HDP * 2);
  u16* kp  = (u16*)alloc((size_t)NHEAD * LTOK * HDP * 2);
  u16* vt  = (u16*)alloc((size_t)NHEAD * HDIM * LTOK * 2);
  u16* att = (u16*)alloc((size_t)LTOK * DMODEL * 2);
  u16* ge  = (u16*)alloc((size_t)LTOK * MLPD * 2);
  // split-K bf16 partial planes: proj -> ge (dead then); MLP2 -> hb+qkvb
  // (dead then; reduce_ln's self-overwrite of plane 0 is program-order safe)
  u16* pk_proj = ge;
  u16* pk_mlp2 = hb;

  hipMemcpyAsync(x, x_in, (size_t)LTOK * DMODEL * sizeof(float),
                 hipMemcpyDeviceToDevice, stream);

  // ONE conversion dispatch for all 4 layers' weights
  cvt4all<<<(NLAY * C3 + 255) / 256, 256, 0, stream>>>(
      qkv_w, proj_w, mlp_w1, mlp_w2, wq, wp, w1, w2);

  for (int l = 0; l < NLAY; l++) {
    const u16* wq_l = wq + (size_t)l * 3 * DMODEL * DMODEL;
    const u16* wp_l = wp + (size_t)l * DMODEL * DMODEL;
    const u16* w1_l = w1 + (size_t)l * MLPD * DMODEL;
    const u16* w2_l = w2 + (size_t)l * DMODEL * MLPD;

    // LN1 (layer 0 only; later layers fused into previous reduce_ln)
    if (l == 0)
      ln_bf16<<<LTOK, 256, 0, stream>>>(x, ln1_g, ln1_b, hb);
    // QKV: 128x256 deep-pipelined, 240 blocks, 4x3 tile-block order
    gemmhp<3, 3><<<dim3(15, 16), 512, 0, stream>>>(
        hb, wq_l, qkv_b + (size_t)l * 3 * DMODEL, qkvb, LTOK, 3 * DMODEL, DMODEL);
    // fused RoPE + V transpose (512 blocks)
    rope_vt<<<NHEAD * 32, 256, 0, stream>>>(qkvb, rpe, qp, kp, vt);
    // attention
    attn<<<NHEAD * 4 * 8, 256, 0, stream>>>(qp, kp, vt, att);
    // x += att @ Wproj^T + b: split-K=4 + fused reduce+LN2
    gemmskb<<<dim3(10, 16, 4), 256, 0, stream>>>(
        att, wp_l, pk_proj, LTOK, DMODEL, DMODEL, DMODEL / 4);
    reduce_ln<<<LTOK, 256, 0, stream>>>(
        pk_proj, proj_b + (size_t)l * DMODEL, x,
        ln2_g + (size_t)l * DMODEL, ln2_b + (size_t)l * DMODEL, hb);
    // ge = gelu(h @ W1^T + b1): 128x256 deep-pipelined, 320 blocks, 4x4 order
    gemmhp<2, 4><<<dim3(20, 16), 512, 0, stream>>>(
        hb, w1_l, mlp_b1 + (size_t)l * MLPD, ge, LTOK, MLPD, DMODEL);
    // x += ge @ W2^T + b2: split-K=4 + fused reduce + next LN1
    gemmskb<<<dim3(10, 16, 4), 256, 0, stream>>>(
        ge, w2_l, pk_mlp2, LTOK, DMODEL, MLPD, MLPD / 4);
    if (l < NLAY - 1)
      reduce_ln<<<LTOK, 256, 0, stream>>>(
          pk_mlp2, mlp_b2 + (size_t)l * DMODEL, x,
          ln1_g + (size_t)(l + 1) * DMODEL, ln1_b + (size_t)(l + 1) * DMODEL, hb);
    else
      reduce4b<<<(N8TOT + 255) / 256, 256, 0, stream>>>(
          pk_mlp2, mlp_b2 + (size_t)l * DMODEL, (float4*)x);
  }
}

// Round 18
// 884.921 us; speedup vs baseline: 1.1228x; 1.1228x over previous
//
#include <hip/hip_runtime.h>
#include <cstdint>
#include <cstddef>

typedef unsigned short u16;
typedef __bf16 bf16_t;
typedef bf16_t bf16x8 __attribute__((ext_vector_type(8)));
typedef float f32x4 __attribute__((ext_vector_type(4)));

#define NLAY 4
#define DMODEL 1280
#define NHEAD 16
#define HDIM 80
#define HDP 96           // padded head dim for QK^T K-loop (3 x 32)
#define MLPD 5120
#define LTOK 2048
#define SEGLEN 512

__device__ __forceinline__ u16 f2bf(float f) {
  union { float f; unsigned u; } x; x.f = f;
  unsigned r = x.u + 0x7fffu + ((x.u >> 16) & 1u);
  return (u16)(r >> 16);
}
__device__ __forceinline__ float bf2f(u16 s) {
  union { unsigned u; float f; } x; x.u = ((unsigned)s) << 16;
  return x.f;
}

#define GLOAD_LDS16(gsrc, ldst) \
  __builtin_amdgcn_global_load_lds((const __attribute__((address_space(1))) void*)(gsrc), \
                                   (__attribute__((address_space(3))) void*)(ldst), 16, 0, 0)

__device__ __forceinline__ void barrier_mem() {
  asm volatile("s_barrier" ::: "memory");
}

// ---------------- all-weights fp32 -> bf16 convert (one layer, one kernel) ----------------
#define C0 (3 * DMODEL * DMODEL / 4)          // qkv_w float4s
#define C1 (C0 + DMODEL * DMODEL / 4)         // + proj_w
#define C2 (C1 + MLPD * DMODEL / 4)           // + mlp_w1
#define C3 (C2 + DMODEL * MLPD / 4)           // + mlp_w2
__global__ __launch_bounds__(256) void cvt4(const float* __restrict__ s_q,
                                            const float* __restrict__ s_p,
                                            const float* __restrict__ s_1,
                                            const float* __restrict__ s_2,
                                            u16* __restrict__ o_q, u16* __restrict__ o_p,
                                            u16* __restrict__ o_1, u16* __restrict__ o_2) {
  int i = blockIdx.x * 256 + threadIdx.x;
  const float* src; u16* dst; int off;
  if (i < C0)      { src = s_q; dst = o_q; off = i; }
  else if (i < C1) { src = s_p; dst = o_p; off = i - C0; }
  else if (i < C2) { src = s_1; dst = o_1; off = i - C1; }
  else if (i < C3) { src = s_2; dst = o_2; off = i - C2; }
  else return;
  const float4 v = reinterpret_cast<const float4*>(src)[off];
  union { u16 s[4]; uint2 u; } o;
  o.s[0] = f2bf(v.x); o.s[1] = f2bf(v.y); o.s[2] = f2bf(v.z); o.s[3] = f2bf(v.w);
  reinterpret_cast<uint2*>(dst)[off] = o.u;
}

// ---------------- LayerNorm (fp32 in, bf16 out) ----------------
__global__ __launch_bounds__(256) void ln_bf16(const float* __restrict__ x,
                                               const float* __restrict__ g,
                                               const float* __restrict__ b,
                                               u16* __restrict__ out) {
  int row = blockIdx.x;
  int t = threadIdx.x;
  const float* xr = x + (size_t)row * DMODEL;
  float v[5]; float s = 0.f, s2 = 0.f;
#pragma unroll
  for (int i = 0; i < 5; i++) { v[i] = xr[t + i * 256]; s += v[i]; s2 += v[i] * v[i]; }
#pragma unroll
  for (int off = 32; off; off >>= 1) { s += __shfl_down(s, off); s2 += __shfl_down(s2, off); }
  __shared__ float ps[4], ps2[4];
  int w = t >> 6;
  if ((t & 63) == 0) { ps[w] = s; ps2[w] = s2; }
  __syncthreads();
  s = ps[0] + ps[1] + ps[2] + ps[3];
  s2 = ps2[0] + ps2[1] + ps2[2] + ps2[3];
  float mean = s * (1.f / DMODEL);
  float var = s2 * (1.f / DMODEL) - mean * mean;
  float inv = rsqrtf(var + 1e-6f);
#pragma unroll
  for (int i = 0; i < 5; i++) {
    int c = t + i * 256;
    out[(size_t)row * DMODEL + c] = f2bf((v[i] - mean) * inv * g[c] + b[c]);
  }
}

// ---- fused split-K reduce + residual + LayerNorm (vectorized) ----
__global__ __launch_bounds__(256) void reduce_ln(const u16* __restrict__ P,
                                                 const float* __restrict__ bias,
                                                 float* __restrict__ x,
                                                 const float* __restrict__ g,
                                                 const float* __restrict__ b,
                                                 u16* __restrict__ out) {
  int row = blockIdx.x;
  int t = threadIdx.x;
  const size_t PS = (size_t)LTOK * DMODEL;
  const size_t base = (size_t)row * DMODEL;
  const int c0 = t * 8;
  float v[8];
  float s = 0.f, s2 = 0.f;
  if (t < DMODEL / 8) {
    float4 x0 = *reinterpret_cast<const float4*>(x + base + c0);
    float4 x1 = *reinterpret_cast<const float4*>(x + base + c0 + 4);
    float4 b0 = *reinterpret_cast<const float4*>(bias + c0);
    float4 b1 = *reinterpret_cast<const float4*>(bias + c0 + 4);
    v[0] = x0.x + b0.x; v[1] = x0.y + b0.y; v[2] = x0.z + b0.z; v[3] = x0.w + b0.w;
    v[4] = x1.x + b1.x; v[5] = x1.y + b1.y; v[6] = x1.z + b1.z; v[7] = x1.w + b1.w;
#pragma unroll
    for (int z = 0; z < 4; z++) {
      uint4 pv = *reinterpret_cast<const uint4*>(P + z * PS + base + c0);
      const u16* ps = (const u16*)&pv;
#pragma unroll
      for (int e = 0; e < 8; e++) v[e] += bf2f(ps[e]);
    }
    float4 o0 = {v[0], v[1], v[2], v[3]};
    float4 o1 = {v[4], v[5], v[6], v[7]};
    *reinterpret_cast<float4*>(x + base + c0) = o0;
    *reinterpret_cast<float4*>(x + base + c0 + 4) = o1;
#pragma unroll
    for (int e = 0; e < 8; e++) { s += v[e]; s2 += v[e] * v[e]; }
  }
#pragma unroll
  for (int off = 32; off; off >>= 1) { s += __shfl_down(s, off); s2 += __shfl_down(s2, off); }
  __shared__ float psh[4], psh2[4];
  int w = t >> 6;
  if ((t & 63) == 0) { psh[w] = s; psh2[w] = s2; }
  __syncthreads();
  s = psh[0] + psh[1] + psh[2] + psh[3];
  s2 = psh2[0] + psh2[1] + psh2[2] + psh2[3];
  float mean = s * (1.f / DMODEL);
  float var = s2 * (1.f / DMODEL) - mean * mean;
  float inv = rsqrtf(var + 1e-6f);
  if (t < DMODEL / 8) {
    float4 g0 = *reinterpret_cast<const float4*>(g + c0);
    float4 g1 = *reinterpret_cast<const float4*>(g + c0 + 4);
    float4 e0 = *reinterpret_cast<const float4*>(b + c0);
    float4 e1 = *reinterpret_cast<const float4*>(b + c0 + 4);
    union { u16 h[8]; uint4 u; } o;
    o.h[0] = f2bf((v[0] - mean) * inv * g0.x + e0.x);
    o.h[1] = f2bf((v[1] - mean) * inv * g0.y + e0.y);
    o.h[2] = f2bf((v[2] - mean) * inv * g0.z + e0.z);
    o.h[3] = f2bf((v[3] - mean) * inv * g0.w + e0.w);
    o.h[4] = f2bf((v[4] - mean) * inv * g1.x + e1.x);
    o.h[5] = f2bf((v[5] - mean) * inv * g1.y + e1.y);
    o.h[6] = f2bf((v[6] - mean) * inv * g1.z + e1.z);
    o.h[7] = f2bf((v[7] - mean) * inv * g1.w + e1.w);
    *reinterpret_cast<uint4*>(out + base + c0) = o.u;
  }
}

// ---------------- deep-pipelined GEMM: 128Mx256N, BK=32, 8 waves, 3-buf counted vmcnt ----
// Hierarchical 4m x NBLKn tile-block ordering inside each XCD chunk.
// EPI 2: Cb = gelu(val + bias); EPI 3: Cb = val + bias
template <int EPI, int NBLK>
__global__ __launch_bounds__(512, 4) void gemmhp(const u16* __restrict__ A,
                                                 const u16* __restrict__ B,
                                                 const float* __restrict__ bias,
                                                 u16* __restrict__ Cb,
                                                 int M, int N, int K) {
  __shared__ u16 As[3][128 * 32];   // 24 KB
  __shared__ u16 Bs[3][256 * 32];   // 48 KB

  int gN = gridDim.x, gM = gridDim.y;
  int flat = blockIdx.x + gN * blockIdx.y;
  int nwg = gN * gM;
  int qc = nwg >> 3, rc = nwg & 7;
  int xcd = flat & 7, pos = flat >> 3;
  int start = (xcd < rc) ? xcd * (qc + 1) : rc * (qc + 1) + (xcd - rc) * qc;
  int swz = start + pos;
  int inn = swz % (4 * NBLK), blk = swz / (4 * NBLK);
  int mi = inn & 3, ni = inn >> 2;
  int bM = gM >> 2;
  int bmi = blk % bM, bni = blk / bM;
  int m0 = (bmi * 4 + mi) * 128;
  int n0 = (bni * NBLK + ni) * 256;

  int t = threadIdx.x, lane = t & 63, w = t >> 6;
  int wm = w >> 2, wn = w & 3;            // 2M x 4N waves, wave tile 64x64
  int r = lane & 15, kq = lane >> 4;
  f32x4 acc[4][4] = {};

  auto stageA = [&](int buf, int k0) {
    int row = t >> 2, s = t & 3;          // 512 chunks = 128 rows x 4 slots
    int ss = s ^ ((row >> 1) & 3);
    GLOAD_LDS16(A + (size_t)(m0 + row) * K + k0 + ss * 8, &As[buf][t * 8]);
  };
  auto stageB = [&](int buf, int k0) {
#pragma unroll
    for (int i = 0; i < 2; i++) {
      int chunk = i * 512 + t;            // 1024 chunks = 256 rows x 4 slots
      int row = chunk >> 2, s = chunk & 3;
      int ss = s ^ ((row >> 1) & 3);
      GLOAD_LDS16(B + (size_t)(n0 + row) * K + k0 + ss * 8, &Bs[buf][chunk * 8]);
    }
  };

  int NT = K >> 5;
  stageA(0, 0); stageB(0, 0);
  stageA(1, 32); stageB(1, 32);

  int bt = 0;
  for (int kt = 0; kt < NT; kt++) {
    if (kt == NT - 1) asm volatile("s_waitcnt vmcnt(0)" ::: "memory");
    else              asm volatile("s_waitcnt vmcnt(3)" ::: "memory");
    barrier_mem();                       // tile kt landed chip-wide
    const u16* as = As[bt];
    const u16* bs = Bs[bt];
    int b2 = bt + 2; if (b2 >= 3) b2 -= 3;
    bool st = (kt + 2) < NT;
    int k2 = (kt + 2) << 5;

    bf16x8 af[4], bfv[4];
#pragma unroll
    for (int i = 0; i < 4; i++) {
      int row = wm * 64 + i * 16 + r;
      int ss = kq ^ ((row >> 1) & 3);
      af[i] = *(const bf16x8*)&as[row * 32 + ss * 8];
    }
#pragma unroll
    for (int j = 0; j < 4; j++) {
      int row = wn * 64 + j * 16 + r;
      int ss = kq ^ ((row >> 1) & 3);
      bfv[j] = *(const bf16x8*)&bs[row * 32 + ss * 8];
    }
    if (st) { stageA(b2, k2); stageB(b2, k2); }
    __builtin_amdgcn_s_setprio(1);
#pragma unroll
    for (int i = 0; i < 4; i++)
#pragma unroll
      for (int j = 0; j < 4; j++)
        acc[i][j] = __builtin_amdgcn_mfma_f32_16x16x32_bf16(af[i], bfv[j], acc[i][j], 0, 0, 0);
    __builtin_amdgcn_s_setprio(0);

    bt++; if (bt == 3) bt = 0;
  }

#pragma unroll
  for (int i = 0; i < 4; i++) {
#pragma unroll
    for (int j = 0; j < 4; j++) {
      int col = n0 + wn * 64 + j * 16 + r;
      float bv = bias[col];
#pragma unroll
      for (int reg = 0; reg < 4; reg++) {
        int rowg = m0 + wm * 64 + i * 16 + kq * 4 + reg;
        float val = acc[i][j][reg] + bv;
        if (EPI == 2) {
          float z2 = -1.5957691216057308f * fmaf(0.044715f * val, val * val, val);
          float gg = val / (1.f + __expf(z2));
          Cb[(size_t)rowg * N + col] = f2bf(gg);
        } else {
          Cb[(size_t)rowg * N + col] = f2bf(val);
        }
      }
    }
  }
}

// ---------------- split-K deep-pipelined GEMM: 128x128, BK=32, 4 waves, bf16 partials --
// (round-12 proven: n-fastest XCD chunks, counted vmcnt(4), 3 buffers)
__global__ __launch_bounds__(256, 3) void gemmskb(const u16* __restrict__ A,
                                                  const u16* __restrict__ B,
                                                  u16* __restrict__ P,
                                                  int M, int N, int K, int KC) {
  __shared__ u16 As[3][128 * 32];   // 24 KB
  __shared__ u16 Bs[3][128 * 32];   // 24 KB

  int gN = gridDim.x, gM = gridDim.y;
  int flat = blockIdx.x + gN * blockIdx.y;
  int nwg = gN * gM;
  int qc = nwg >> 3, rc = nwg & 7;
  int xcd = flat & 7, pos = flat >> 3;
  int start = (xcd < rc) ? xcd * (qc + 1) : rc * (qc + 1) + (xcd - rc) * qc;
  int swz = start + pos;
  int n0 = (swz % gN) * 128;            // n-fastest within chunk
  int m0 = (swz / gN) * 128;
  int kbase = blockIdx.z * KC;
  u16* Pz = P + (size_t)blockIdx.z * M * N;

  int t = threadIdx.x, lane = t & 63, w = t >> 6;
  int wm = w >> 1, wn = w & 1;            // 2M x 2N waves, wave tile 64x64
  int r = lane & 15, kq = lane >> 4;
  f32x4 acc[4][4] = {};

  auto stage = [&](int buf, int k0) {
#pragma unroll
    for (int i = 0; i < 2; i++) {
      int chunk = i * 256 + t;            // 512 chunks = 128 rows x 4 slots
      int row = chunk >> 2, s = chunk & 3;
      int ss = s ^ ((row >> 1) & 3);
      GLOAD_LDS16(A + (size_t)(m0 + row) * K + k0 + ss * 8, &As[buf][chunk * 8]);
    }
#pragma unroll
    for (int i = 0; i < 2; i++) {
      int chunk = i * 256 + t;
      int row = chunk >> 2, s = chunk & 3;
      int ss = s ^ ((row >> 1) & 3);
      GLOAD_LDS16(B + (size_t)(n0 + row) * K + k0 + ss * 8, &Bs[buf][chunk * 8]);
    }
  };

  int NT = KC >> 5;
  stage(0, kbase);
  stage(1, kbase + 32);

  int bt = 0;
  for (int kt = 0; kt < NT; kt++) {
    if (kt == NT - 1) asm volatile("s_waitcnt vmcnt(0)" ::: "memory");
    else              asm volatile("s_waitcnt vmcnt(4)" ::: "memory");
    barrier_mem();                       // tile kt landed chip-wide
    const u16* as = As[bt];
    const u16* bs = Bs[bt];
    int b2 = bt + 2; if (b2 >= 3) b2 -= 3;
    bool st = (kt + 2) < NT;
    int k2 = kbase + ((kt + 2) << 5);

    bf16x8 af[4], bfv[4];
#pragma unroll
    for (int i = 0; i < 4; i++) {
      int row = wm * 64 + i * 16 + r;
      int ss = kq ^ ((row >> 1) & 3);
      af[i] = *(const bf16x8*)&as[row * 32 + ss * 8];
    }
#pragma unroll
    for (int j = 0; j < 4; j++) {
      int row = wn * 64 + j * 16 + r;
      int ss = kq ^ ((row >> 1) & 3);
      bfv[j] = *(const bf16x8*)&bs[row * 32 + ss * 8];
    }
    if (st) stage(b2, k2);
    __builtin_amdgcn_s_setprio(1);
#pragma unroll
    for (int i = 0; i < 4; i++)
#pragma unroll
      for (int j = 0; j < 4; j++)
        acc[i][j] = __builtin_amdgcn_mfma_f32_16x16x32_bf16(af[i], bfv[j], acc[i][j], 0, 0, 0);
    __builtin_amdgcn_s_setprio(0);

    bt++; if (bt == 3) bt = 0;
  }

#pragma unroll
  for (int i = 0; i < 4; i++) {
#pragma unroll
    for (int j = 0; j < 4; j++) {
      int col = n0 + wn * 64 + j * 16 + r;
#pragma unroll
      for (int reg = 0; reg < 4; reg++) {
        int rowg = m0 + wm * 64 + i * 16 + kq * 4 + reg;
        Pz[(size_t)rowg * N + col] = f2bf(acc[i][j][reg]);
      }
    }
  }
}

// ---------------- reduce 4 bf16 split-K partials + bias into residual x ----------------
#define N8TOT (LTOK * DMODEL / 8)
__global__ __launch_bounds__(256) void reduce4b(const u16* __restrict__ P,
                                                const float* __restrict__ bias,
                                                float4* __restrict__ x) {
  int i = blockIdx.x * 256 + threadIdx.x;
  if (i >= N8TOT) return;
  const size_t PS = (size_t)LTOK * DMODEL;
  float s[8] = {};
#pragma unroll
  for (int z = 0; z < 4; z++) {
    uint4 pv = *reinterpret_cast<const uint4*>(P + z * PS + (size_t)i * 8);
    const u16* ps = (const u16*)&pv;
#pragma unroll
    for (int e = 0; e < 8; e++) s[e] += bf2f(ps[e]);
  }
  int cb = (i % (DMODEL / 8)) * 8;
  float4 b0 = *reinterpret_cast<const float4*>(bias + cb);
  float4 b1 = *reinterpret_cast<const float4*>(bias + cb + 4);
  float4 xv0 = x[i * 2], xv1 = x[i * 2 + 1];
  xv0.x += s[0] + b0.x; xv0.y += s[1] + b0.y;
  xv0.z += s[2] + b0.z; xv0.w += s[3] + b0.w;
  xv1.x += s[4] + b1.x; xv1.y += s[5] + b1.y;
  xv1.z += s[6] + b1.z; xv1.w += s[7] + b1.w;
  x[i * 2] = xv0; x[i * 2 + 1] = xv1;
}

// ---------------- RoPE + pack q,k into (NH, L, HDP) bf16, q scaled ----------------
__global__ __launch_bounds__(256) void rope_pack(const u16* __restrict__ qkv,
                                                 const float* __restrict__ rpe,
                                                 u16* __restrict__ qp,
                                                 u16* __restrict__ kp) {
  int l = blockIdx.x;
  int t = threadIdx.x;
  __shared__ float cs[40], sn[40];
  if (t < 40) {
    float a = rpe[l * 40 + t];
    cs[t] = cosf(a);
    sn[t] = sinf(a);
  }
  __syncthreads();
  const u16* row = qkv + (size_t)l * (3 * DMODEL);
  const float scale = 0.11180339887498949f;  // 1/sqrt(80)
#pragma unroll
  for (int i = 0; i < 5; i++) {
    int e = t + i * 256;
    int h = e / HDIM, d = e - h * HDIM;
    int dm = (d < 40) ? d : d - 40;
    float c = cs[dm], s = sn[dm];
    float qv = bf2f(row[h * HDIM + d]);
    float qr = (d < 40) ? -bf2f(row[h * HDIM + d + 40]) : bf2f(row[h * HDIM + d - 40]);
    qp[((size_t)h * LTOK + l) * HDP + d] = f2bf((qv * c + qr * s) * scale);
    float kv = bf2f(row[DMODEL + h * HDIM + d]);
    float kr = (d < 40) ? -bf2f(row[DMODEL + h * HDIM + d + 40]) : bf2f(row[DMODEL + h * HDIM + d - 40]);
    kp[((size_t)h * LTOK + l) * HDP + d] = f2bf(kv * c + kr * s);
  }
  // zero the pad [80,96)
  {
    int h = t >> 4, p = t & 15;
    qp[((size_t)h * LTOK + l) * HDP + HDIM + p] = 0;
    kp[((size_t)h * LTOK + l) * HDP + HDIM + p] = 0;
  }
}

// ---------------- V transpose: (L, NH, HD) bf16 slice of qkv -> (NH, HD, L) bf16 ----------------
__global__ __launch_bounds__(256) void vtrans(const u16* __restrict__ qkv,
                                              u16* __restrict__ vt) {
  int blk = blockIdx.x;
  int h = blk >> 5, lt = blk & 31;
  int t = threadIdx.x;
  __shared__ u16 ld[64][81];
#pragma unroll
  for (int i = 0; i < 20; i++) {
    int idx = t + i * 256;
    int ll = idx / HDIM, d = idx - ll * HDIM;
    ld[ll][d] = qkv[(size_t)(lt * 64 + ll) * (3 * DMODEL) + 2 * DMODEL + h * HDIM + d];
  }
  __syncthreads();
#pragma unroll
  for (int i = 0; i < 20; i++) {
    int idx = t + i * 256;
    int d = idx >> 6, ll = idx & 63;
    vt[((size_t)h * HDIM + d) * LTOK + lt * 64 + ll] = ld[ll][d];
  }
}

// ---------------- Attention: per (head, seg, 64-row q-tile) ----------------
__global__ __launch_bounds__(256) void attn(const u16* __restrict__ qp,
                                            const u16* __restrict__ kp,
                                            const u16* __restrict__ vt,
                                            u16* __restrict__ out) {
  int bid = blockIdx.x;               // h*32 + seg*8 + qt
  int h = bid >> 5;
  int seg = (bid >> 3) & 3;
  int qt = bid & 7;
  int t = threadIdx.x, w = t >> 6, lane = t & 63;
  int r = lane & 15, kq = lane >> 4;
  __shared__ u16 P[4][16][512];
  int seg0 = seg * SEGLEN;
  int q0 = seg0 + qt * 64 + w * 16;

  bf16x8 qf[3];
  const u16* qrow = qp + ((size_t)h * LTOK + q0 + r) * HDP;
#pragma unroll
  for (int kk = 0; kk < 3; kk++) qf[kk] = *(const bf16x8*)(qrow + kk * 32 + kq * 8);

  f32x4 sc[32];
#pragma unroll
  for (int j = 0; j < 32; j++) {
    f32x4 a = {0.f, 0.f, 0.f, 0.f};
    const u16* krow = kp + ((size_t)h * LTOK + seg0 + j * 16 + r) * HDP;
#pragma unroll
    for (int kk = 0; kk < 3; kk++) {
      bf16x8 bfr = *(const bf16x8*)(krow + kk * 32 + kq * 8);
      a = __builtin_amdgcn_mfma_f32_16x16x32_bf16(qf[kk], bfr, a, 0, 0, 0);
    }
    sc[j] = a;
  }

#pragma unroll
  for (int rr = 0; rr < 4; rr++) {
    float m = -1e30f;
#pragma unroll
    for (int j = 0; j < 32; j++) m = fmaxf(m, sc[j][rr]);
#pragma unroll
    for (int off = 1; off < 16; off <<= 1) m = fmaxf(m, __shfl_xor(m, off));
    float s = 0.f;
#pragma unroll
    for (int j = 0; j < 32; j++) { float e = __expf(sc[j][rr] - m); sc[j][rr] = e; s += e; }
#pragma unroll
    for (int off = 1; off < 16; off <<= 1) s += __shfl_xor(s, off);
    float inv = 1.f / s;
#pragma unroll
    for (int j = 0; j < 32; j++)
      P[w][kq * 4 + rr][j * 16 + r] = f2bf(sc[j][rr] * inv);
  }
  __syncthreads();

  f32x4 oc[5] = {};
#pragma unroll
  for (int tt = 0; tt < 16; tt++) {
    bf16x8 a = *(const bf16x8*)&P[w][r][tt * 32 + kq * 8];
#pragma unroll
    for (int n = 0; n < 5; n++) {
      const u16* vrow = vt + ((size_t)h * HDIM + n * 16 + r) * LTOK + seg0 + tt * 32 + kq * 8;
      bf16x8 bfr = *(const bf16x8*)vrow;
      oc[n] = __builtin_amdgcn_mfma_f32_16x16x32_bf16(a, bfr, oc[n], 0, 0, 0);
    }
  }
#pragma unroll
  for (int n = 0; n < 5; n++)
#pragma unroll
    for (int reg = 0; reg < 4; reg++) {
      int l = q0 + kq * 4 + reg;
      out[(size_t)l * DMODEL + h * HDIM + n * 16 + r] = f2bf(oc[n][reg]);
    }
}

// ---------------- host launch ----------------
extern "C" void kernel_launch(void* const* d_in, const int* in_sizes, int n_in,
                              void* d_out, int out_size, void* d_ws, size_t ws_size,
                              hipStream_t stream) {
  (void)in_sizes; (void)n_in; (void)out_size; (void)ws_size;
  const float* x_in   = (const float*)d_in[0];
  const float* rpe    = (const float*)d_in[1];
  const float* ln1_g  = (const float*)d_in[3];
  const float* ln1_b  = (const float*)d_in[4];
  const float* ln2_g  = (const float*)d_in[5];
  const float* ln2_b  = (const float*)d_in[6];
  const float* qkv_w  = (const float*)d_in[7];
  const float* qkv_b  = (const float*)d_in[8];
  const float* proj_w = (const float*)d_in[9];
  const float* proj_b = (const float*)d_in[10];
  const float* mlp_w1 = (const float*)d_in[11];
  const float* mlp_b1 = (const float*)d_in[12];
  const float* mlp_w2 = (const float*)d_in[13];
  const float* mlp_b2 = (const float*)d_in[14];
  float* x = (float*)d_out;

  char* ws = (char*)d_ws;
  size_t off = 0;
  auto alloc = [&](size_t bytes) -> char* {
    char* p = ws + off;
    off = (off + bytes + 255) & ~(size_t)255;
    return p;
  };
  u16* wq  = (u16*)alloc((size_t)3 * DMODEL * DMODEL * 2);
  u16* wp  = (u16*)alloc((size_t)DMODEL * DMODEL * 2);
  u16* w1  = (u16*)alloc((size_t)MLPD * DMODEL * 2);
  u16* w2  = (u16*)alloc((size_t)DMODEL * MLPD * 2);
  u16* hb  = (u16*)alloc((size_t)LTOK * DMODEL * 2);
  u16* qkvb = (u16*)alloc((size_t)LTOK * 3 * DMODEL * 2);
  u16* qp  = (u16*)alloc((size_t)NHEAD * LTOK * HDP * 2);
  u16* kp  = (u16*)alloc((size_t)NHEAD * LTOK * HDP * 2);
  u16* vt  = (u16*)alloc((size_t)NHEAD * HDIM * LTOK * 2);
  u16* att = (u16*)alloc((size_t)LTOK * DMODEL * 2);
  u16* ge  = (u16*)alloc((size_t)LTOK * MLPD * 2);
  // split-K bf16 partial planes: proj -> ge (dead then); MLP2 -> hb+qkvb
  // (dead then; reduce_ln's self-overwrite of plane 0 is program-order safe)
  u16* pk_proj = ge;
  u16* pk_mlp2 = hb;

  hipMemcpyAsync(x, x_in, (size_t)LTOK * DMODEL * sizeof(float),
                 hipMemcpyDeviceToDevice, stream);

  for (int l = 0; l < NLAY; l++) {
    cvt4<<<(C3 + 255) / 256, 256, 0, stream>>>(
        qkv_w + (size_t)l * 3 * DMODEL * DMODEL, proj_w + (size_t)l * DMODEL * DMODEL,
        mlp_w1 + (size_t)l * MLPD * DMODEL, mlp_w2 + (size_t)l * DMODEL * MLPD,
        wq, wp, w1, w2);

    // LN1 (layer 0 only; later layers fused into previous reduce_ln)
    if (l == 0)
      ln_bf16<<<LTOK, 256, 0, stream>>>(x, ln1_g, ln1_b, hb);
    // QKV: 128x256 deep-pipelined, 240 blocks, 4x3 tile-block order
    gemmhp<3, 3><<<dim3(15, 16), 512, 0, stream>>>(
        hb, wq, qkv_b + (size_t)l * 3 * DMODEL, qkvb, LTOK, 3 * DMODEL, DMODEL);
    // RoPE + pack q,k ; transpose v
    rope_pack<<<LTOK, 256, 0, stream>>>(qkvb, rpe, qp, kp);
    vtrans<<<NHEAD * 32, 256, 0, stream>>>(qkvb, vt);
    // attention
    attn<<<NHEAD * 4 * 8, 256, 0, stream>>>(qp, kp, vt, att);
    // x += att @ Wproj^T + b: split-K=4 + fused reduce+LN2
    gemmskb<<<dim3(10, 16, 4), 256, 0, stream>>>(
        att, wp, pk_proj, LTOK, DMODEL, DMODEL, DMODEL / 4);
    reduce_ln<<<LTOK, 256, 0, stream>>>(
        pk_proj, proj_b + (size_t)l * DMODEL, x,
        ln2_g + (size_t)l * DMODEL, ln2_b + (size_t)l * DMODEL, hb);
    // ge = gelu(h @ W1^T + b1): 128x256 deep-pipelined, 320 blocks, 4x4 order
    gemmhp<2, 4><<<dim3(20, 16), 512, 0, stream>>>(
        hb, w1, mlp_b1 + (size_t)l * MLPD, ge, LTOK, MLPD, DMODEL);
    // x += ge @ W2^T + b2: split-K=4 + fused reduce + next LN1
    gemmskb<<<dim3(10, 16, 4), 256, 0, stream>>>(
        ge, w2, pk_mlp2, LTOK, DMODEL, MLPD, MLPD / 4);
    if (l < NLAY - 1)
      reduce_ln<<<LTOK, 256, 0, stream>>>(
          pk_mlp2, mlp_b2 + (size_t)l * DMODEL, x,
          ln1_g + (size_t)(l + 1) * DMODEL, ln1_b + (size_t)(l + 1) * DMODEL, hb);
    else
      reduce4b<<<(N8TOT + 255) / 256, 256, 0, stream>>>(
          pk_mlp2, mlp_b2 + (size_t)l * DMODEL, (float4*)x);
  }
}

// Round 19
// 877.913 us; speedup vs baseline: 1.1317x; 1.0080x over previous
//
#include <hip/hip_runtime.h>
#include <cstdint>
#include <cstddef>

typedef unsigned short u16;
typedef __bf16 bf16_t;
typedef bf16_t bf16x8 __attribute__((ext_vector_type(8)));
typedef float f32x4 __attribute__((ext_vector_type(4)));

#define NLAY 4
#define DMODEL 1280
#define NHEAD 16
#define HDIM 80
#define HDP 96           // padded head dim for QK^T K-loop (3 x 32)
#define MLPD 5120
#define LTOK 2048
#define SEGLEN 512

__device__ __forceinline__ u16 f2bf(float f) {
  union { float f; unsigned u; } x; x.f = f;
  unsigned r = x.u + 0x7fffu + ((x.u >> 16) & 1u);
  return (u16)(r >> 16);
}
__device__ __forceinline__ float bf2f(u16 s) {
  union { unsigned u; float f; } x; x.u = ((unsigned)s) << 16;
  return x.f;
}

#define GLOAD_LDS16(gsrc, ldst) \
  __builtin_amdgcn_global_load_lds((const __attribute__((address_space(1))) void*)(gsrc), \
                                   (__attribute__((address_space(3))) void*)(ldst), 16, 0, 0)

__device__ __forceinline__ void barrier_mem() {
  asm volatile("s_barrier" ::: "memory");
}

// ---------------- all-weights fp32 -> bf16 convert (one layer, one kernel) ----------------
#define C0 (3 * DMODEL * DMODEL / 4)          // qkv_w float4s
#define C1 (C0 + DMODEL * DMODEL / 4)         // + proj_w
#define C2 (C1 + MLPD * DMODEL / 4)           // + mlp_w1
#define C3 (C2 + DMODEL * MLPD / 4)           // + mlp_w2
__global__ __launch_bounds__(256) void cvt4(const float* __restrict__ s_q,
                                            const float* __restrict__ s_p,
                                            const float* __restrict__ s_1,
                                            const float* __restrict__ s_2,
                                            u16* __restrict__ o_q, u16* __restrict__ o_p,
                                            u16* __restrict__ o_1, u16* __restrict__ o_2) {
  int i = blockIdx.x * 256 + threadIdx.x;
  const float* src; u16* dst; int off;
  if (i < C0)      { src = s_q; dst = o_q; off = i; }
  else if (i < C1) { src = s_p; dst = o_p; off = i - C0; }
  else if (i < C2) { src = s_1; dst = o_1; off = i - C1; }
  else if (i < C3) { src = s_2; dst = o_2; off = i - C2; }
  else return;
  const float4 v = reinterpret_cast<const float4*>(src)[off];
  union { u16 s[4]; uint2 u; } o;
  o.s[0] = f2bf(v.x); o.s[1] = f2bf(v.y); o.s[2] = f2bf(v.z); o.s[3] = f2bf(v.w);
  reinterpret_cast<uint2*>(dst)[off] = o.u;
}

// ---------------- LayerNorm (fp32 in, bf16 out) ----------------
__global__ __launch_bounds__(256) void ln_bf16(const float* __restrict__ x,
                                               const float* __restrict__ g,
                                               const float* __restrict__ b,
                                               u16* __restrict__ out) {
  int row = blockIdx.x;
  int t = threadIdx.x;
  const float* xr = x + (size_t)row * DMODEL;
  float v[5]; float s = 0.f, s2 = 0.f;
#pragma unroll
  for (int i = 0; i < 5; i++) { v[i] = xr[t + i * 256]; s += v[i]; s2 += v[i] * v[i]; }
#pragma unroll
  for (int off = 32; off; off >>= 1) { s += __shfl_down(s, off); s2 += __shfl_down(s2, off); }
  __shared__ float ps[4], ps2[4];
  int w = t >> 6;
  if ((t & 63) == 0) { ps[w] = s; ps2[w] = s2; }
  __syncthreads();
  s = ps[0] + ps[1] + ps[2] + ps[3];
  s2 = ps2[0] + ps2[1] + ps2[2] + ps2[3];
  float mean = s * (1.f / DMODEL);
  float var = s2 * (1.f / DMODEL) - mean * mean;
  float inv = rsqrtf(var + 1e-6f);
#pragma unroll
  for (int i = 0; i < 5; i++) {
    int c = t + i * 256;
    out[(size_t)row * DMODEL + c] = f2bf((v[i] - mean) * inv * g[c] + b[c]);
  }
}

// ---- fused split-K reduce + residual + LayerNorm: one block per row ----
// x[row] += sum_z P[z][row] + bias; then out = LN(x[row]) * g + b (bf16).
// Safe when P plane 0 aliases `out`: each block reads only its own row's
// partials (per-thread, before the stats barrier) and writes the same
// addresses strictly after.
__global__ __launch_bounds__(256) void reduce_ln(const u16* __restrict__ P,
                                                 const float* __restrict__ bias,
                                                 float* __restrict__ x,
                                                 const float* __restrict__ g,
                                                 const float* __restrict__ b,
                                                 u16* __restrict__ out) {
  int row = blockIdx.x;
  int t = threadIdx.x;
  const size_t PS = (size_t)LTOK * DMODEL;
  const size_t base = (size_t)row * DMODEL;
  float v[5]; float s = 0.f, s2 = 0.f;
#pragma unroll
  for (int i = 0; i < 5; i++) {
    int c = t + i * 256;
    float val = x[base + c] + bias[c];
#pragma unroll
    for (int z = 0; z < 4; z++) val += bf2f(P[z * PS + base + c]);
    x[base + c] = val;
    v[i] = val; s += val; s2 += val * val;
  }
#pragma unroll
  for (int off = 32; off; off >>= 1) { s += __shfl_down(s, off); s2 += __shfl_down(s2, off); }
  __shared__ float ps[4], ps2[4];
  int w = t >> 6;
  if ((t & 63) == 0) { ps[w] = s; ps2[w] = s2; }
  __syncthreads();
  s = ps[0] + ps[1] + ps[2] + ps[3];
  s2 = ps2[0] + ps2[1] + ps2[2] + ps2[3];
  float mean = s * (1.f / DMODEL);
  float var = s2 * (1.f / DMODEL) - mean * mean;
  float inv = rsqrtf(var + 1e-6f);
#pragma unroll
  for (int i = 0; i < 5; i++) {
    int c = t + i * 256;
    out[base + c] = f2bf((v[i] - mean) * inv * g[c] + b[c]);
  }
}

// ---------------- deep-pipelined GEMM: 128Mx256N, BK=32, 8 waves, 3-buf counted vmcnt ----
// (round-8/12 proven: m-fastest XCD-chunk ordering)
// EPI 2: Cb = gelu(val + bias); EPI 3: Cb = val + bias
template <int EPI>
__global__ __launch_bounds__(512, 4) void gemmhp(const u16* __restrict__ A,
                                                 const u16* __restrict__ B,
                                                 const float* __restrict__ bias,
                                                 u16* __restrict__ Cb,
                                                 int M, int N, int K) {
  __shared__ u16 As[3][128 * 32];   // 24 KB
  __shared__ u16 Bs[3][256 * 32];   // 48 KB

  int gN = gridDim.x, gM = gridDim.y;
  int flat = blockIdx.x + gN * blockIdx.y;
  int nwg = gN * gM;
  int qc = nwg >> 3, rc = nwg & 7;
  int xcd = flat & 7, pos = flat >> 3;
  int start = (xcd < rc) ? xcd * (qc + 1) : rc * (qc + 1) + (xcd - rc) * qc;
  int swz = start + pos;
  int m0 = (swz % gM) * 128;
  int n0 = (swz / gM) * 256;

  int t = threadIdx.x, lane = t & 63, w = t >> 6;
  int wm = w >> 2, wn = w & 3;            // 2M x 4N waves, wave tile 64x64
  int r = lane & 15, kq = lane >> 4;
  f32x4 acc[4][4] = {};

  auto stageA = [&](int buf, int k0) {
    int row = t >> 2, s = t & 3;          // 512 chunks = 128 rows x 4 slots
    int ss = s ^ ((row >> 1) & 3);
    GLOAD_LDS16(A + (size_t)(m0 + row) * K + k0 + ss * 8, &As[buf][t * 8]);
  };
  auto stageB = [&](int buf, int k0) {
#pragma unroll
    for (int i = 0; i < 2; i++) {
      int chunk = i * 512 + t;            // 1024 chunks = 256 rows x 4 slots
      int row = chunk >> 2, s = chunk & 3;
      int ss = s ^ ((row >> 1) & 3);
      GLOAD_LDS16(B + (size_t)(n0 + row) * K + k0 + ss * 8, &Bs[buf][chunk * 8]);
    }
  };

  int NT = K >> 5;
  stageA(0, 0); stageB(0, 0);
  stageA(1, 32); stageB(1, 32);

  int bt = 0;
  for (int kt = 0; kt < NT; kt++) {
    if (kt == NT - 1) asm volatile("s_waitcnt vmcnt(0)" ::: "memory");
    else              asm volatile("s_waitcnt vmcnt(3)" ::: "memory");
    barrier_mem();                       // tile kt landed chip-wide
    const u16* as = As[bt];
    const u16* bs = Bs[bt];
    int b2 = bt + 2; if (b2 >= 3) b2 -= 3;
    bool st = (kt + 2) < NT;
    int k2 = (kt + 2) << 5;

    bf16x8 af[4], bfv[4];
#pragma unroll
    for (int i = 0; i < 4; i++) {
      int row = wm * 64 + i * 16 + r;
      int ss = kq ^ ((row >> 1) & 3);
      af[i] = *(const bf16x8*)&as[row * 32 + ss * 8];
    }
#pragma unroll
    for (int j = 0; j < 4; j++) {
      int row = wn * 64 + j * 16 + r;
      int ss = kq ^ ((row >> 1) & 3);
      bfv[j] = *(const bf16x8*)&bs[row * 32 + ss * 8];
    }
    if (st) { stageA(b2, k2); stageB(b2, k2); }
    __builtin_amdgcn_s_setprio(1);
#pragma unroll
    for (int i = 0; i < 4; i++)
#pragma unroll
      for (int j = 0; j < 4; j++)
        acc[i][j] = __builtin_amdgcn_mfma_f32_16x16x32_bf16(af[i], bfv[j], acc[i][j], 0, 0, 0);
    __builtin_amdgcn_s_setprio(0);

    bt++; if (bt == 3) bt = 0;
  }

#pragma unroll
  for (int i = 0; i < 4; i++) {
#pragma unroll
    for (int j = 0; j < 4; j++) {
      int col = n0 + wn * 64 + j * 16 + r;
      float bv = bias[col];
#pragma unroll
      for (int reg = 0; reg < 4; reg++) {
        int rowg = m0 + wm * 64 + i * 16 + kq * 4 + reg;
        float val = acc[i][j][reg] + bv;
        if (EPI == 2) {
          float z2 = -1.5957691216057308f * fmaf(0.044715f * val, val * val, val);
          float gg = val / (1.f + __expf(z2));
          Cb[(size_t)rowg * N + col] = f2bf(gg);
        } else {
          Cb[(size_t)rowg * N + col] = f2bf(val);
        }
      }
    }
  }
}

// ---------------- split-K deep-pipelined GEMM: 128x128, BK=32, 4 waves, bf16 partials --
// (round-12 proven: n-fastest XCD chunks, counted vmcnt(4), 3 buffers)
__global__ __launch_bounds__(256, 3) void gemmskb(const u16* __restrict__ A,
                                                  const u16* __restrict__ B,
                                                  u16* __restrict__ P,
                                                  int M, int N, int K, int KC) {
  __shared__ u16 As[3][128 * 32];   // 24 KB
  __shared__ u16 Bs[3][128 * 32];   // 24 KB

  int gN = gridDim.x, gM = gridDim.y;
  int flat = blockIdx.x + gN * blockIdx.y;
  int nwg = gN * gM;
  int qc = nwg >> 3, rc = nwg & 7;
  int xcd = flat & 7, pos = flat >> 3;
  int start = (xcd < rc) ? xcd * (qc + 1) : rc * (qc + 1) + (xcd - rc) * qc;
  int swz = start + pos;
  int n0 = (swz % gN) * 128;            // n-fastest within chunk
  int m0 = (swz / gN) * 128;
  int kbase = blockIdx.z * KC;
  u16* Pz = P + (size_t)blockIdx.z * M * N;

  int t = threadIdx.x, lane = t & 63, w = t >> 6;
  int wm = w >> 1, wn = w & 1;            // 2M x 2N waves, wave tile 64x64
  int r = lane & 15, kq = lane >> 4;
  f32x4 acc[4][4] = {};

  auto stage = [&](int buf, int k0) {
#pragma unroll
    for (int i = 0; i < 2; i++) {
      int chunk = i * 256 + t;            // 512 chunks = 128 rows x 4 slots
      int row = chunk >> 2, s = chunk & 3;
      int ss = s ^ ((row >> 1) & 3);
      GLOAD_LDS16(A + (size_t)(m0 + row) * K + k0 + ss * 8, &As[buf][chunk * 8]);
    }
#pragma unroll
    for (int i = 0; i < 2; i++) {
      int chunk = i * 256 + t;
      int row = chunk >> 2, s = chunk & 3;
      int ss = s ^ ((row >> 1) & 3);
      GLOAD_LDS16(B + (size_t)(n0 + row) * K + k0 + ss * 8, &Bs[buf][chunk * 8]);
    }
  };

  int NT = KC >> 5;
  stage(0, kbase);
  stage(1, kbase + 32);

  int bt = 0;
  for (int kt = 0; kt < NT; kt++) {
    if (kt == NT - 1) asm volatile("s_waitcnt vmcnt(0)" ::: "memory");
    else              asm volatile("s_waitcnt vmcnt(4)" ::: "memory");
    barrier_mem();                       // tile kt landed chip-wide
    const u16* as = As[bt];
    const u16* bs = Bs[bt];
    int b2 = bt + 2; if (b2 >= 3) b2 -= 3;
    bool st = (kt + 2) < NT;
    int k2 = kbase + ((kt + 2) << 5);

    bf16x8 af[4], bfv[4];
#pragma unroll
    for (int i = 0; i < 4; i++) {
      int row = wm * 64 + i * 16 + r;
      int ss = kq ^ ((row >> 1) & 3);
      af[i] = *(const bf16x8*)&as[row * 32 + ss * 8];
    }
#pragma unroll
    for (int j = 0; j < 4; j++) {
      int row = wn * 64 + j * 16 + r;
      int ss = kq ^ ((row >> 1) & 3);
      bfv[j] = *(const bf16x8*)&bs[row * 32 + ss * 8];
    }
    if (st) stage(b2, k2);
    __builtin_amdgcn_s_setprio(1);
#pragma unroll
    for (int i = 0; i < 4; i++)
#pragma unroll
      for (int j = 0; j < 4; j++)
        acc[i][j] = __builtin_amdgcn_mfma_f32_16x16x32_bf16(af[i], bfv[j], acc[i][j], 0, 0, 0);
    __builtin_amdgcn_s_setprio(0);

    bt++; if (bt == 3) bt = 0;
  }

#pragma unroll
  for (int i = 0; i < 4; i++) {
#pragma unroll
    for (int j = 0; j < 4; j++) {
      int col = n0 + wn * 64 + j * 16 + r;
#pragma unroll
      for (int reg = 0; reg < 4; reg++) {
        int rowg = m0 + wm * 64 + i * 16 + kq * 4 + reg;
        Pz[(size_t)rowg * N + col] = f2bf(acc[i][j][reg]);
      }
    }
  }
}

// ---------------- reduce 4 bf16 split-K partials + bias into residual x ----------------
#define N8TOT (LTOK * DMODEL / 8)
__global__ __launch_bounds__(256) void reduce4b(const u16* __restrict__ P,
                                                const float* __restrict__ bias,
                                                float4* __restrict__ x) {
  int i = blockIdx.x * 256 + threadIdx.x;
  if (i >= N8TOT) return;
  const size_t PS = (size_t)LTOK * DMODEL;
  float s[8] = {};
#pragma unroll
  for (int z = 0; z < 4; z++) {
    uint4 pv = *reinterpret_cast<const uint4*>(P + z * PS + (size_t)i * 8);
    const u16* ps = (const u16*)&pv;
#pragma unroll
    for (int e = 0; e < 8; e++) s[e] += bf2f(ps[e]);
  }
  int cb = (i % (DMODEL / 8)) * 8;
  float4 b0 = *reinterpret_cast<const float4*>(bias + cb);
  float4 b1 = *reinterpret_cast<const float4*>(bias + cb + 4);
  float4 xv0 = x[i * 2], xv1 = x[i * 2 + 1];
  xv0.x += s[0] + b0.x; xv0.y += s[1] + b0.y;
  xv0.z += s[2] + b0.z; xv0.w += s[3] + b0.w;
  xv1.x += s[4] + b1.x; xv1.y += s[5] + b1.y;
  xv1.z += s[6] + b1.z; xv1.w += s[7] + b1.w;
  x[i * 2] = xv0; x[i * 2 + 1] = xv1;
}

// ---------------- RoPE + pack q,k into (NH, L, HDP) bf16, q scaled ----------------
__global__ __launch_bounds__(256) void rope_pack(const u16* __restrict__ qkv,
                                                 const float* __restrict__ rpe,
                                                 u16* __restrict__ qp,
                                                 u16* __restrict__ kp) {
  int l = blockIdx.x;
  int t = threadIdx.x;
  __shared__ float cs[40], sn[40];
  if (t < 40) {
    float a = rpe[l * 40 + t];
    cs[t] = cosf(a);
    sn[t] = sinf(a);
  }
  __syncthreads();
  const u16* row = qkv + (size_t)l * (3 * DMODEL);
  const float scale = 0.11180339887498949f;  // 1/sqrt(80)
#pragma unroll
  for (int i = 0; i < 5; i++) {
    int e = t + i * 256;
    int h = e / HDIM, d = e - h * HDIM;
    int dm = (d < 40) ? d : d - 40;
    float c = cs[dm], s = sn[dm];
    float qv = bf2f(row[h * HDIM + d]);
    float qr = (d < 40) ? -bf2f(row[h * HDIM + d + 40]) : bf2f(row[h * HDIM + d - 40]);
    qp[((size_t)h * LTOK + l) * HDP + d] = f2bf((qv * c + qr * s) * scale);
    float kv = bf2f(row[DMODEL + h * HDIM + d]);
    float kr = (d < 40) ? -bf2f(row[DMODEL + h * HDIM + d + 40]) : bf2f(row[DMODEL + h * HDIM + d - 40]);
    kp[((size_t)h * LTOK + l) * HDP + d] = f2bf(kv * c + kr * s);
  }
  // zero the pad [80,96)
  {
    int h = t >> 4, p = t & 15;
    qp[((size_t)h * LTOK + l) * HDP + HDIM + p] = 0;
    kp[((size_t)h * LTOK + l) * HDP + HDIM + p] = 0;
  }
}

// ---------------- V transpose: (L, NH, HD) bf16 slice of qkv -> (NH, HD, L) bf16 ----------------
__global__ __launch_bounds__(256) void vtrans(const u16* __restrict__ qkv,
                                              u16* __restrict__ vt) {
  int blk = blockIdx.x;
  int h = blk >> 5, lt = blk & 31;
  int t = threadIdx.x;
  __shared__ u16 ld[64][81];
#pragma unroll
  for (int i = 0; i < 20; i++) {
    int idx = t + i * 256;
    int ll = idx / HDIM, d = idx - ll * HDIM;
    ld[ll][d] = qkv[(size_t)(lt * 64 + ll) * (3 * DMODEL) + 2 * DMODEL + h * HDIM + d];
  }
  __syncthreads();
#pragma unroll
  for (int i = 0; i < 20; i++) {
    int idx = t + i * 256;
    int d = idx >> 6, ll = idx & 63;
    vt[((size_t)h * HDIM + d) * LTOK + lt * 64 + ll] = ld[ll][d];
  }
}

// ---------------- Attention: per (head, seg, 64-row q-tile) ----------------
__global__ __launch_bounds__(256) void attn(const u16* __restrict__ qp,
                                            const u16* __restrict__ kp,
                                            const u16* __restrict__ vt,
                                            u16* __restrict__ out) {
  int bid = blockIdx.x;               // h*32 + seg*8 + qt
  int h = bid >> 5;
  int seg = (bid >> 3) & 3;
  int qt = bid & 7;
  int t = threadIdx.x, w = t >> 6, lane = t & 63;
  int r = lane & 15, kq = lane >> 4;
  __shared__ u16 P[4][16][512];
  int seg0 = seg * SEGLEN;
  int q0 = seg0 + qt * 64 + w * 16;

  bf16x8 qf[3];
  const u16* qrow = qp + ((size_t)h * LTOK + q0 + r) * HDP;
#pragma unroll
  for (int kk = 0; kk < 3; kk++) qf[kk] = *(const bf16x8*)(qrow + kk * 32 + kq * 8);

  f32x4 sc[32];
#pragma unroll
  for (int j = 0; j < 32; j++) {
    f32x4 a = {0.f, 0.f, 0.f, 0.f};
    const u16* krow = kp + ((size_t)h * LTOK + seg0 + j * 16 + r) * HDP;
#pragma unroll
    for (int kk = 0; kk < 3; kk++) {
      bf16x8 bfr = *(const bf16x8*)(krow + kk * 32 + kq * 8);
      a = __builtin_amdgcn_mfma_f32_16x16x32_bf16(qf[kk], bfr, a, 0, 0, 0);
    }
    sc[j] = a;
  }

#pragma unroll
  for (int rr = 0; rr < 4; rr++) {
    float m = -1e30f;
#pragma unroll
    for (int j = 0; j < 32; j++) m = fmaxf(m, sc[j][rr]);
#pragma unroll
    for (int off = 1; off < 16; off <<= 1) m = fmaxf(m, __shfl_xor(m, off));
    float s = 0.f;
#pragma unroll
    for (int j = 0; j < 32; j++) { float e = __expf(sc[j][rr] - m); sc[j][rr] = e; s += e; }
#pragma unroll
    for (int off = 1; off < 16; off <<= 1) s += __shfl_xor(s, off);
    float inv = 1.f / s;
#pragma unroll
    for (int j = 0; j < 32; j++)
      P[w][kq * 4 + rr][j * 16 + r] = f2bf(sc[j][rr] * inv);
  }
  __syncthreads();

  f32x4 oc[5] = {};
#pragma unroll
  for (int tt = 0; tt < 16; tt++) {
    bf16x8 a = *(const bf16x8*)&P[w][r][tt * 32 + kq * 8];
#pragma unroll
    for (int n = 0; n < 5; n++) {
      const u16* vrow = vt + ((size_t)h * HDIM + n * 16 + r) * LTOK + seg0 + tt * 32 + kq * 8;
      bf16x8 bfr = *(const bf16x8*)vrow;
      oc[n] = __builtin_amdgcn_mfma_f32_16x16x32_bf16(a, bfr, oc[n], 0, 0, 0);
    }
  }
#pragma unroll
  for (int n = 0; n < 5; n++)
#pragma unroll
    for (int reg = 0; reg < 4; reg++) {
      int l = q0 + kq * 4 + reg;
      out[(size_t)l * DMODEL + h * HDIM + n * 16 + r] = f2bf(oc[n][reg]);
    }
}

// ---------------- host launch ----------------
extern "C" void kernel_launch(void* const* d_in, const int* in_sizes, int n_in,
                              void* d_out, int out_size, void* d_ws, size_t ws_size,
                              hipStream_t stream) {
  (void)in_sizes; (void)n_in; (void)out_size; (void)ws_size;
  const float* x_in   = (const float*)d_in[0];
  const float* rpe    = (const float*)d_in[1];
  const float* ln1_g  = (const float*)d_in[3];
  const float* ln1_b  = (const float*)d_in[4];
  const float* ln2_g  = (const float*)d_in[5];
  const float* ln2_b  = (const float*)d_in[6];
  const float* qkv_w  = (const float*)d_in[7];
  const float* qkv_b  = (const float*)d_in[8];
  const float* proj_w = (const float*)d_in[9];
  const float* proj_b = (const float*)d_in[10];
  const float* mlp_w1 = (const float*)d_in[11];
  const float* mlp_b1 = (const float*)d_in[12];
  const float* mlp_w2 = (const float*)d_in[13];
  const float* mlp_b2 = (const float*)d_in[14];
  float* x = (float*)d_out;

  char* ws = (char*)d_ws;
  size_t off = 0;
  auto alloc = [&](size_t bytes) -> char* {
    char* p = ws + off;
    off = (off + bytes + 255) & ~(size_t)255;
    return p;
  };
  u16* wq  = (u16*)alloc((size_t)3 * DMODEL * DMODEL * 2);
  u16* wp  = (u16*)alloc((size_t)DMODEL * DMODEL * 2);
  u16* w1  = (u16*)alloc((size_t)MLPD * DMODEL * 2);
  u16* w2  = (u16*)alloc((size_t)DMODEL * MLPD * 2);
  u16* hb  = (u16*)alloc((size_t)LTOK * DMODEL * 2);
  u16* qkvb = (u16*)alloc((size_t)LTOK * 3 * DMODEL * 2);
  u16* qp  = (u16*)alloc((size_t)NHEAD * LTOK * HDP * 2);
  u16* kp  = (u16*)alloc((size_t)NHEAD * LTOK * HDP * 2);
  u16* vt  = (u16*)alloc((size_t)NHEAD * HDIM * LTOK * 2);
  u16* att = (u16*)alloc((size_t)LTOK * DMODEL * 2);
  u16* ge  = (u16*)alloc((size_t)LTOK * MLPD * 2);
  // split-K bf16 partial planes (4 x 2048x1280 bf16 = 21 MB each set):
  //  - proj partials alias ge          (dead during proj + its reduce)
  //  - MLP2 partials alias hb+qkvb     (dead during MLP2 + its reduce;
  //    reduce_ln's self-overwrite of plane 0 (= hb) is program-order safe)
  u16* pk_proj = ge;
  u16* pk_mlp2 = hb;

  hipMemcpyAsync(x, x_in, (size_t)LTOK * DMODEL * sizeof(float),
                 hipMemcpyDeviceToDevice, stream);

  for (int l = 0; l < NLAY; l++) {
    cvt4<<<(C3 + 255) / 256, 256, 0, stream>>>(
        qkv_w + (size_t)l * 3 * DMODEL * DMODEL, proj_w + (size_t)l * DMODEL * DMODEL,
        mlp_w1 + (size_t)l * MLPD * DMODEL, mlp_w2 + (size_t)l * DMODEL * MLPD,
        wq, wp, w1, w2);

    // LN1 (layer 0 only; later layers fused into previous reduce_ln)
    if (l == 0)
      ln_bf16<<<LTOK, 256, 0, stream>>>(x, ln1_g, ln1_b, hb);
    // QKV: 128x256 deep-pipelined, 240 blocks
    gemmhp<3><<<dim3(15, 16), 512, 0, stream>>>(
        hb, wq, qkv_b + (size_t)l * 3 * DMODEL, qkvb, LTOK, 3 * DMODEL, DMODEL);
    // RoPE + pack q,k ; transpose v
    rope_pack<<<LTOK, 256, 0, stream>>>(qkvb, rpe, qp, kp);
    vtrans<<<NHEAD * 32, 256, 0, stream>>>(qkvb, vt);
    // attention
    attn<<<NHEAD * 4 * 8, 256, 0, stream>>>(qp, kp, vt, att);
    // x += att @ Wproj^T + b: split-K=4 + fused reduce+LN2
    gemmskb<<<dim3(10, 16, 4), 256, 0, stream>>>(
        att, wp, pk_proj, LTOK, DMODEL, DMODEL, DMODEL / 4);
    reduce_ln<<<LTOK, 256, 0, stream>>>(
        pk_proj, proj_b + (size_t)l * DMODEL, x,
        ln2_g + (size_t)l * DMODEL, ln2_b + (size_t)l * DMODEL, hb);
    // ge = gelu(h @ W1^T + b1): 128x256 deep-pipelined, 320 blocks
    gemmhp<2><<<dim3(20, 16), 512, 0, stream>>>(
        hb, w1, mlp_b1 + (size_t)l * MLPD, ge, LTOK, MLPD, DMODEL);
    // x += ge @ W2^T + b2: split-K=4 + fused reduce + next LN1
    gemmskb<<<dim3(10, 16, 4), 256, 0, stream>>>(
        ge, w2, pk_mlp2, LTOK, DMODEL, MLPD, MLPD / 4);
    if (l < NLAY - 1)
      reduce_ln<<<LTOK, 256, 0, stream>>>(
          pk_mlp2, mlp_b2 + (size_t)l * DMODEL, x,
          ln1_g + (size_t)(l + 1) * DMODEL, ln1_b + (size_t)(l + 1) * DMODEL, hb);
    else
      reduce4b<<<(N8TOT + 255) / 256, 256, 0, stream>>>(
          pk_mlp2, mlp_b2 + (size_t)l * DMODEL, (float4*)x);
  }
}